// Round 8
// baseline (66.976 us; speedup 1.0000x reference)
//
#include <hip/hip_runtime.h>
#include <math.h>

// SSIM loss. Tile = 256(x) x 32(y) outputs per 256-thread block; thread owns
// one column. 1024 blocks -> 4 blocks/CU (R7 had 512 blocks/2-per-CU and
// measured OccupancyPercent 20.5% -> latency-bound on barrier convoying).
//  - rolling 4-row group of (p=sigmoid(logits), g=gts) staged in LDS,
//    column-major [266][4], double-buffered -> 1 barrier/group
//  - horizontal 11-tap conv: combined single pass, 22 ds_read_b128/group
//  - vertical 11-tap conv: shift window, 14 pending slots x 5 fields in
//    registers, all indices static (R4 mod-ring spilled; R5 (512,4) cap
//    spilled; (NT,2) budget + static shift is the proven-safe combo)
// Horizontal halo (10 cols) loads real neighbor data; zeros outside image.

#define KW 11
#define HALF 5
#define STRIP 32              // output rows per block
#define TW 256                // output cols per block
#define W 512
#define H 512
#define NT 256
#define NGRP 11               // 11 groups x 4 rows = 44 (rows 42,43 masked)
#define NIN (STRIP + 2*HALF)  // 42
#define SCOL (TW + 2*HALF)    // 266 staged columns
#define NSLOT 14

static constexpr float kC1 = 0.0001f;   // 0.01^2
static constexpr float kC2 = 0.0009f;   // 0.03^2

__global__ __launch_bounds__(NT, 2) void ssim_tile(
    const float* __restrict__ logits,
    const float* __restrict__ gts,
    const float* __restrict__ window,
    float* __restrict__ partial)
{
    __shared__ float sp[2][SCOL][4];
    __shared__ float sg[2][SCOL][4];
    __shared__ float red[NT / 64];

    const int x = threadIdx.x;

    // 1D taps = row sums of 2D window (sum(g)=1); SGPR-hoist via bitcast
    // (readfirstlane is int-typed; R3 bug was float->int truncation).
    float w[KW];
#pragma unroll
    for (int k = 0; k < KW; ++k) {
        float s = 0.f;
#pragma unroll
        for (int j = 0; j < KW; ++j) s += window[k * KW + j];
        w[k] = __int_as_float(__builtin_amdgcn_readfirstlane(__float_as_int(s)));
    }

    const int tpi = (H / STRIP) * (W / TW);   // 16*2 = 32 tiles per image
    const int img = blockIdx.x / tpi;
    const int t   = blockIdx.x % tpi;
    const int ty  = t >> 1;
    const int y0  = ty * STRIP;
    const int x0  = (t & 1) * TW;             // tile's leftmost image col
    const float* __restrict__ L = logits + (size_t)img * (H * W);
    const float* __restrict__ G = gts    + (size_t)img * (H * W);

    // pending output-row accumulators (static indices only!)
    float P1[NSLOT], P2[NSLOT], PA[NSLOT], PB[NSLOT], PC[NSLOT];
#pragma unroll
    for (int i = 0; i < NSLOT; ++i) {
        P1[i] = 0.f; P2[i] = 0.f; PA[i] = 0.f; PB[i] = 0.f; PC[i] = 0.f;
    }

    // prefetch group 0 (input rows y0-5 .. y0-2); i=1 covers cols 256..265
    float pl[2][4], pgv[2][4];
#pragma unroll
    for (int i = 0; i < 2; ++i) {
#pragma unroll
        for (int j = 0; j < 4; ++j) {
            const int c  = x + NT * i;               // staged col
            const int xc = x0 + c - HALF;            // image col
            const int row = y0 - HALF + j;
            const bool v = (c < SCOL) && (xc >= 0) && (xc < W) &&
                           (row >= 0) && (row < H);
            pl[i][j]  = v ? L[(size_t)row * W + xc] : 0.f;
            pgv[i][j] = v ? G[(size_t)row * W + xc] : 0.f;
        }
    }

    float acc = 0.f;

    for (int g = 0; g < NGRP; ++g) {
        const int b = g & 1;

        // ---- stage group g into buffer b (sigmoid; zeros outside) ----
#pragma unroll
        for (int i = 0; i < 2; ++i) {
            const int c = x + NT * i;
            if (c < SCOL) {
                float stp[4], stg[4];
#pragma unroll
                for (int j = 0; j < 4; ++j) {
                    const int rr = 4 * g + j;
                    const bool v = (rr < NIN);
                    stp[j] = v ? 1.f / (1.f + __expf(-pl[i][j])) : 0.f;
                    // pl/pgv already zeroed for out-of-image positions, but
                    // sigmoid(0)=0.5 -> must mask; gts mask keeps 0.
                    stp[j] = (v && (pl[i][j] != 0.f || true)) ? stp[j] : 0.f;
                    stg[j] = v ? pgv[i][j] : 0.f;
                }
                // NOTE: out-of-image rows/cols must stage p=0 (not 0.5).
                // Recompute validity explicitly:
#pragma unroll
                for (int j = 0; j < 4; ++j) {
                    const int rr = 4 * g + j;
                    const int row = y0 - HALF + rr;
                    const int xc = x0 + c - HALF;
                    const bool vv = (rr < NIN) && (row >= 0) && (row < H) &&
                                    (xc >= 0) && (xc < W);
                    if (!vv) { stp[j] = 0.f; stg[j] = 0.f; }
                }
                *(float4*)(&sp[b][c][0]) = make_float4(stp[0], stp[1], stp[2], stp[3]);
                *(float4*)(&sg[b][c][0]) = make_float4(stg[0], stg[1], stg[2], stg[3]);
            }
        }

        // ---- prefetch group g+1 (overlaps barrier + compute) ----
        if (g + 1 < NGRP) {
#pragma unroll
            for (int i = 0; i < 2; ++i) {
#pragma unroll
                for (int j = 0; j < 4; ++j) {
                    const int c  = x + NT * i;
                    const int xc = x0 + c - HALF;
                    const int rr = 4 * (g + 1) + j;
                    const int row = y0 - HALF + rr;
                    const bool v = (c < SCOL) && (xc >= 0) && (xc < W) &&
                                   (rr < NIN) && (row >= 0) && (row < H);
                    pl[i][j]  = v ? L[(size_t)row * W + xc] : 0.f;
                    pgv[i][j] = v ? G[(size_t)row * W + xc] : 0.f;
                }
            }
        }

        // Single barrier per group (double-buffered; reuse distance = 2 groups)
        __syncthreads();

        // ---- combined horizontal conv: one pass, all 5 fields ----
        float h1[4] = {0,0,0,0}, h2[4] = {0,0,0,0};
        float hA[4] = {0,0,0,0}, hB[4] = {0,0,0,0}, hC[4] = {0,0,0,0};
#pragma unroll
        for (int k = 0; k < KW; ++k) {
            const float4 pq = *(const float4*)(&sp[b][x + k][0]);
            const float4 gq = *(const float4*)(&sg[b][x + k][0]);
            const float wk = w[k];
            h1[0] += wk * pq.x;        h1[1] += wk * pq.y;
            h1[2] += wk * pq.z;        h1[3] += wk * pq.w;
            h2[0] += wk * gq.x;        h2[1] += wk * gq.y;
            h2[2] += wk * gq.z;        h2[3] += wk * gq.w;
            hA[0] += wk * pq.x * pq.x; hA[1] += wk * pq.y * pq.y;
            hA[2] += wk * pq.z * pq.z; hA[3] += wk * pq.w * pq.w;
            hB[0] += wk * gq.x * gq.x; hB[1] += wk * gq.y * gq.y;
            hB[2] += wk * gq.z * gq.z; hB[3] += wk * gq.w * gq.w;
            hC[0] += wk * pq.x * gq.x; hC[1] += wk * pq.y * gq.y;
            hC[2] += wk * pq.z * gq.z; hC[3] += wk * pq.w * gq.w;
        }

        // ---- scatter rows into pending slots (all indices static) ----
#pragma unroll
        for (int j = 0; j < 4; ++j) {
#pragma unroll
            for (int d = 0; d <= 10; ++d) {
                const int p = j + d;          // slot, static
                const float wk = w[10 - d];
                P1[p] += wk * h1[j];
                P2[p] += wk * h2[j];
                PA[p] += wk * hA[j];
                PB[p] += wk * hB[j];
                PC[p] += wk * hC[j];
            }
        }

        // ---- emit completed slots 0..3 (oo = 4g-10+p), then shift by 4 ----
        const int oo0 = 4 * g - 10;
#pragma unroll
        for (int p = 0; p < 4; ++p) {
            const int oo = oo0 + p;           // uniform scalar bound check
            if (oo >= 0 && oo < STRIP) {
                const float m1 = P1[p], m2 = P2[p];
                const float mu11 = m1 * m1, mu22 = m2 * m2, mu12 = m1 * m2;
                const float s11 = PA[p] - mu11;
                const float s22 = PB[p] - mu22;
                const float s12 = PC[p] - mu12;
                const float num = (2.f * mu12 + kC1) * (2.f * s12 + kC2);
                const float den = (mu11 + mu22 + kC1) * (s11 + s22 + kC2);
                acc += num * __builtin_amdgcn_rcpf(den);
            }
        }
#pragma unroll
        for (int i = 0; i < NSLOT - 4; ++i) {
            P1[i] = P1[i + 4]; P2[i] = P2[i + 4];
            PA[i] = PA[i + 4]; PB[i] = PB[i + 4]; PC[i] = PC[i + 4];
        }
#pragma unroll
        for (int i = NSLOT - 4; i < NSLOT; ++i) {
            P1[i] = 0.f; P2[i] = 0.f; PA[i] = 0.f; PB[i] = 0.f; PC[i] = 0.f;
        }
    }

    // ---- block reduction ----
#pragma unroll
    for (int off = 32; off > 0; off >>= 1) acc += __shfl_xor(acc, off);
    if ((x & 63) == 0) red[x >> 6] = acc;
    __syncthreads();
    if (x == 0) {
        float s = 0.f;
#pragma unroll
        for (int i = 0; i < NT / 64; ++i) s += red[i];
        partial[blockIdx.x] = s;
    }
}

__global__ __launch_bounds__(256) void ssim_finalize(
    const float* __restrict__ partial, int nparts, double inv_count,
    float* __restrict__ out)
{
    __shared__ double sd[256];
    const int tid = threadIdx.x;
    double s = 0.0;
    for (int i = tid; i < nparts; i += 256) s += (double)partial[i];
    sd[tid] = s;
    __syncthreads();
    for (int st = 128; st > 0; st >>= 1) {
        if (tid < st) sd[tid] += sd[tid + st];
        __syncthreads();
    }
    if (tid == 0) out[0] = (float)(1.0 - sd[0] * inv_count);
}

extern "C" void kernel_launch(void* const* d_in, const int* in_sizes, int n_in,
                              void* d_out, int out_size, void* d_ws, size_t ws_size,
                              hipStream_t stream) {
    const float* logits = (const float*)d_in[0];
    const float* gts    = (const float*)d_in[1];
    const float* window = (const float*)d_in[2];
    float* out = (float*)d_out;

    const int nimg = in_sizes[0] / (H * W);                 // 32
    const int nblocks = nimg * (H / STRIP) * (W / TW);      // 1024

    float* partial = (float*)d_ws;

    ssim_tile<<<nblocks, NT, 0, stream>>>(logits, gts, window, partial);

    const double inv_count = 1.0 / ((double)nimg * H * W);
    ssim_finalize<<<1, 256, 0, stream>>>(partial, nblocks, inv_count, out);
}

// Round 10
// 58.575 us; speedup vs baseline: 1.1434x; 1.1434x over previous
//
#include <hip/hip_runtime.h>
#include <math.h>

// SSIM loss. 512-wide x 32-row strip per 512-thread block (R7 base, best).
// R9 changes, all aimed at VALU instruction count (R8 showed occupancy is
// not the lever; implied ~12.5K inst/thread vs ~6K core):
//  - sigmoid via rcpf, computed at prefetch time (masked with scalar mul)
//  - uniform row clamp -> unconditional loads, no per-lane bounds masks
//  - tail-peel rows 40,41 -> main loop g=0..9 has no rr<NIN masks
//  - vertical scatter via v_dot2_f32_f16 pairs (220 FMA -> 120 dot2),
//    weight pairs SGPR-hoisted; f16 err ~5e-4 << 2e-2 tolerance
// R9 compile fix: cvt_pkrtz returns a __fp16 vector, not _Float16 ->
// derive the pair type with decltype.

#define KW 11
#define HALF 5
#define STRIP 32
#define W 512
#define H 512
#define NT 512
#define SCOLS (W + 2*HALF)    // 522
#define NSLOT 14

static constexpr float kC1 = 0.0001f;
static constexpr float kC2 = 0.0009f;

typedef decltype(__builtin_amdgcn_cvt_pkrtz(0.f, 0.f)) half2v;

__device__ __forceinline__ float sgpr_f(float v) {
    return __int_as_float(__builtin_amdgcn_readfirstlane(__float_as_int(v)));
}

__global__ __launch_bounds__(NT, 2) void ssim_strip(
    const float* __restrict__ logits,
    const float* __restrict__ gts,
    const float* __restrict__ window,
    float* __restrict__ partial)
{
    __shared__ float sp[2][SCOLS][4];
    __shared__ float sg[2][SCOLS][4];
    __shared__ float red[NT / 64];

    const int x = threadIdx.x;

    // 1D taps = row sums of 2D window (sum(g)=1); SGPR-hoisted.
    float w[KW];
#pragma unroll
    for (int k = 0; k < KW; ++k) {
        float s = 0.f;
#pragma unroll
        for (int j = 0; j < KW; ++j) s += window[k * KW + j];
        w[k] = sgpr_f(s);
    }

    // f16 weight pairs for the vertical scatter, SGPR-hoisted as bits.
    // slot p gets row j with weight w[10-(p-j)]:
    //   rows (0,1): (w[10-p], w[11-p])   valid p=0..11
    //   rows (2,3): (w[12-p], w[13-p])   valid p=2..13
    int wpAi[12], wpBi[12];
#pragma unroll
    for (int p = 0; p < 12; ++p) {
        const float a0 = (10 - p >= 0 && 10 - p <= 10) ? w[10 - p] : 0.f;
        const float a1 = (11 - p >= 0 && 11 - p <= 10) ? w[11 - p] : 0.f;
        wpAi[p] = __builtin_amdgcn_readfirstlane(
            __builtin_bit_cast(int, __builtin_amdgcn_cvt_pkrtz(a0, a1)));
        const int q = p + 2;
        const float b0 = (12 - q >= 0 && 12 - q <= 10) ? w[12 - q] : 0.f;
        const float b1 = (13 - q >= 0 && 13 - q <= 10) ? w[13 - q] : 0.f;
        wpBi[p] = __builtin_amdgcn_readfirstlane(
            __builtin_bit_cast(int, __builtin_amdgcn_cvt_pkrtz(b0, b1)));
    }

    const int img = blockIdx.x >> 4;
    const int ty  = blockIdx.x & 15;
    const int y0  = ty * STRIP;
    const float* __restrict__ L = logits + (size_t)img * (H * W);
    const float* __restrict__ G = gts    + (size_t)img * (H * W);

    // zero halo columns once, both buffers
    if (x < 2 * HALF) {
        const int sc = (x < HALF) ? x : (W + x);
#pragma unroll
        for (int b = 0; b < 2; ++b)
#pragma unroll
            for (int r = 0; r < 4; ++r) { sp[b][sc][r] = 0.f; sg[b][sc][r] = 0.f; }
    }

    float P1[NSLOT], P2[NSLOT], PA[NSLOT], PB[NSLOT], PC[NSLOT];
#pragma unroll
    for (int i = 0; i < NSLOT; ++i) {
        P1[i] = 0.f; P2[i] = 0.f; PA[i] = 0.f; PB[i] = 0.f; PC[i] = 0.f;
    }

    // prefetch+preprocess: pl = masked sigmoid(logit), pgv = masked gt
    float pl[4], pgv[4];
#define PREFETCH_ROW(j, rr_expr)                                               \
    {                                                                          \
        const int row  = y0 - HALF + (rr_expr);                                \
        const int rowc = min(max(row, 0), H - 1);                              \
        const float mk = (row == rowc) ? 1.f : 0.f;                            \
        const float lv = L[rowc * W + x];                                      \
        const float gv = G[rowc * W + x];                                      \
        pl[j]  = mk * __builtin_amdgcn_rcpf(1.f + __expf(-lv));                \
        pgv[j] = mk * gv;                                                      \
    }
#pragma unroll
    for (int j = 0; j < 4; ++j) PREFETCH_ROW(j, j)

    float acc = 0.f;

    for (int g = 0; g < 10; ++g) {
        const int b = g & 1;

        // stage group g (already sigmoided+masked)
        *(float4*)(&sp[b][x + HALF][0]) = make_float4(pl[0], pl[1], pl[2], pl[3]);
        *(float4*)(&sg[b][x + HALF][0]) = make_float4(pgv[0], pgv[1], pgv[2], pgv[3]);

        // prefetch next (rows of g+1, or tail rows 40,41 when g==9)
        if (g < 9) {
#pragma unroll
            for (int j = 0; j < 4; ++j) PREFETCH_ROW(j, 4 * (g + 1) + j)
        } else {
#pragma unroll
            for (int j = 0; j < 2; ++j) PREFETCH_ROW(j, 40 + j)
        }

        __syncthreads();   // double-buffered: one barrier per group

        // combined horizontal conv, all 5 fields, 22 ds_read_b128
        float h1[4] = {0,0,0,0}, h2[4] = {0,0,0,0};
        float hA[4] = {0,0,0,0}, hB[4] = {0,0,0,0}, hC[4] = {0,0,0,0};
#pragma unroll
        for (int k = 0; k < KW; ++k) {
            const float4 pq = *(const float4*)(&sp[b][x + k][0]);
            const float4 gq = *(const float4*)(&sg[b][x + k][0]);
            const float wk = w[k];
            h1[0] += wk * pq.x;        h1[1] += wk * pq.y;
            h1[2] += wk * pq.z;        h1[3] += wk * pq.w;
            h2[0] += wk * gq.x;        h2[1] += wk * gq.y;
            h2[2] += wk * gq.z;        h2[3] += wk * gq.w;
            hA[0] += wk * pq.x * pq.x; hA[1] += wk * pq.y * pq.y;
            hA[2] += wk * pq.z * pq.z; hA[3] += wk * pq.w * pq.w;
            hB[0] += wk * gq.x * gq.x; hB[1] += wk * gq.y * gq.y;
            hB[2] += wk * gq.z * gq.z; hB[3] += wk * gq.w * gq.w;
            hC[0] += wk * pq.x * gq.x; hC[1] += wk * pq.y * gq.y;
            hC[2] += wk * pq.z * gq.z; hC[3] += wk * pq.w * gq.w;
        }

        // vertical scatter via f16 dot2 pairs (rows 0,1 then rows 2,3)
        {
            const half2v q1 = __builtin_amdgcn_cvt_pkrtz(h1[0], h1[1]);
            const half2v q2 = __builtin_amdgcn_cvt_pkrtz(h2[0], h2[1]);
            const half2v qA = __builtin_amdgcn_cvt_pkrtz(hA[0], hA[1]);
            const half2v qB = __builtin_amdgcn_cvt_pkrtz(hB[0], hB[1]);
            const half2v qC = __builtin_amdgcn_cvt_pkrtz(hC[0], hC[1]);
#pragma unroll
            for (int p = 0; p < 12; ++p) {
                const half2v wa = __builtin_bit_cast(half2v, wpAi[p]);
                P1[p] = __builtin_amdgcn_fdot2(q1, wa, P1[p], false);
                P2[p] = __builtin_amdgcn_fdot2(q2, wa, P2[p], false);
                PA[p] = __builtin_amdgcn_fdot2(qA, wa, PA[p], false);
                PB[p] = __builtin_amdgcn_fdot2(qB, wa, PB[p], false);
                PC[p] = __builtin_amdgcn_fdot2(qC, wa, PC[p], false);
            }
        }
        {
            const half2v q1 = __builtin_amdgcn_cvt_pkrtz(h1[2], h1[3]);
            const half2v q2 = __builtin_amdgcn_cvt_pkrtz(h2[2], h2[3]);
            const half2v qA = __builtin_amdgcn_cvt_pkrtz(hA[2], hA[3]);
            const half2v qB = __builtin_amdgcn_cvt_pkrtz(hB[2], hB[3]);
            const half2v qC = __builtin_amdgcn_cvt_pkrtz(hC[2], hC[3]);
#pragma unroll
            for (int p = 2; p < 14; ++p) {
                const half2v wb = __builtin_bit_cast(half2v, wpBi[p - 2]);
                P1[p] = __builtin_amdgcn_fdot2(q1, wb, P1[p], false);
                P2[p] = __builtin_amdgcn_fdot2(q2, wb, P2[p], false);
                PA[p] = __builtin_amdgcn_fdot2(qA, wb, PA[p], false);
                PB[p] = __builtin_amdgcn_fdot2(qB, wb, PB[p], false);
                PC[p] = __builtin_amdgcn_fdot2(qC, wb, PC[p], false);
            }
        }

        // emit slots 0..3 (oo = 4g-10+p), shift window by 4
        const int oo0 = 4 * g - 10;
#pragma unroll
        for (int p = 0; p < 4; ++p) {
            const int oo = oo0 + p;
            if (oo >= 0) {     // max oo in main loop = 29 < STRIP
                const float m1 = P1[p], m2 = P2[p];
                const float mu11 = m1 * m1, mu22 = m2 * m2, mu12 = m1 * m2;
                const float s11 = PA[p] - mu11;
                const float s22 = PB[p] - mu22;
                const float s12 = PC[p] - mu12;
                const float num = (2.f * mu12 + kC1) * (2.f * s12 + kC2);
                const float den = (mu11 + mu22 + kC1) * (s11 + s22 + kC2);
                acc += num * __builtin_amdgcn_rcpf(den);
            }
        }
#pragma unroll
        for (int i = 0; i < NSLOT - 4; ++i) {
            P1[i] = P1[i + 4]; P2[i] = P2[i + 4];
            PA[i] = PA[i + 4]; PB[i] = PB[i + 4]; PC[i] = PC[i + 4];
        }
#pragma unroll
        for (int i = NSLOT - 4; i < NSLOT; ++i) {
            P1[i] = 0.f; P2[i] = 0.f; PA[i] = 0.f; PB[i] = 0.f; PC[i] = 0.f;
        }
    }

    // ---- tail: rows 40,41 into buffer 0; emit oo=30,31 (slots 0,1) ----
    *(float2*)(&sp[0][x + HALF][0]) = make_float2(pl[0], pl[1]);
    *(float2*)(&sg[0][x + HALF][0]) = make_float2(pgv[0], pgv[1]);
    __syncthreads();
    {
        float h1[2] = {0,0}, h2[2] = {0,0}, hA[2] = {0,0}, hB[2] = {0,0}, hC[2] = {0,0};
#pragma unroll
        for (int k = 0; k < KW; ++k) {
            const float2 pq = *(const float2*)(&sp[0][x + k][0]);
            const float2 gq = *(const float2*)(&sg[0][x + k][0]);
            const float wk = w[k];
            h1[0] += wk * pq.x;        h1[1] += wk * pq.y;
            h2[0] += wk * gq.x;        h2[1] += wk * gq.y;
            hA[0] += wk * pq.x * pq.x; hA[1] += wk * pq.y * pq.y;
            hB[0] += wk * gq.x * gq.x; hB[1] += wk * gq.y * gq.y;
            hC[0] += wk * pq.x * gq.x; hC[1] += wk * pq.y * gq.y;
        }
        const half2v q1 = __builtin_amdgcn_cvt_pkrtz(h1[0], h1[1]);
        const half2v q2 = __builtin_amdgcn_cvt_pkrtz(h2[0], h2[1]);
        const half2v qA = __builtin_amdgcn_cvt_pkrtz(hA[0], hA[1]);
        const half2v qB = __builtin_amdgcn_cvt_pkrtz(hB[0], hB[1]);
        const half2v qC = __builtin_amdgcn_cvt_pkrtz(hC[0], hC[1]);
#pragma unroll
        for (int p = 0; p < 12; ++p) {
            const half2v wa = __builtin_bit_cast(half2v, wpAi[p]);
            P1[p] = __builtin_amdgcn_fdot2(q1, wa, P1[p], false);
            P2[p] = __builtin_amdgcn_fdot2(q2, wa, P2[p], false);
            PA[p] = __builtin_amdgcn_fdot2(qA, wa, PA[p], false);
            PB[p] = __builtin_amdgcn_fdot2(qB, wa, PB[p], false);
            PC[p] = __builtin_amdgcn_fdot2(qC, wa, PC[p], false);
        }
#pragma unroll
        for (int p = 0; p < 2; ++p) {   // oo = 30, 31
            const float m1 = P1[p], m2 = P2[p];
            const float mu11 = m1 * m1, mu22 = m2 * m2, mu12 = m1 * m2;
            const float s11 = PA[p] - mu11;
            const float s22 = PB[p] - mu22;
            const float s12 = PC[p] - mu12;
            const float num = (2.f * mu12 + kC1) * (2.f * s12 + kC2);
            const float den = (mu11 + mu22 + kC1) * (s11 + s22 + kC2);
            acc += num * __builtin_amdgcn_rcpf(den);
        }
    }

    // block reduction
#pragma unroll
    for (int off = 32; off > 0; off >>= 1) acc += __shfl_xor(acc, off);
    if ((x & 63) == 0) red[x >> 6] = acc;
    __syncthreads();
    if (x == 0) {
        float s = 0.f;
#pragma unroll
        for (int i = 0; i < NT / 64; ++i) s += red[i];
        partial[blockIdx.x] = s;
    }
#undef PREFETCH_ROW
}

__global__ __launch_bounds__(256) void ssim_finalize(
    const float* __restrict__ partial, int nparts, double inv_count,
    float* __restrict__ out)
{
    __shared__ double sd[256];
    const int tid = threadIdx.x;
    double s = 0.0;
    for (int i = tid; i < nparts; i += 256) s += (double)partial[i];
    sd[tid] = s;
    __syncthreads();
    for (int st = 128; st > 0; st >>= 1) {
        if (tid < st) sd[tid] += sd[tid + st];
        __syncthreads();
    }
    if (tid == 0) out[0] = (float)(1.0 - sd[0] * inv_count);
}

extern "C" void kernel_launch(void* const* d_in, const int* in_sizes, int n_in,
                              void* d_out, int out_size, void* d_ws, size_t ws_size,
                              hipStream_t stream) {
    const float* logits = (const float*)d_in[0];
    const float* gts    = (const float*)d_in[1];
    const float* window = (const float*)d_in[2];
    float* out = (float*)d_out;

    const int nimg = in_sizes[0] / (H * W);   // 32
    const int nblocks = nimg * (H / STRIP);   // 512

    float* partial = (float*)d_ws;

    ssim_strip<<<nblocks, NT, 0, stream>>>(logits, gts, window, partial);

    const double inv_count = 1.0 / ((double)nimg * H * W);
    ssim_finalize<<<1, 256, 0, stream>>>(partial, nblocks, inv_count, out);
}

// Round 11
// 40.763 us; speedup vs baseline: 1.6431x; 1.4369x over previous
//
#include <hip/hip_runtime.h>
#include <math.h>

// SSIM loss. 512-wide x 32-row strip per 512-thread block.
// R11: f16-packed LDS staging + packed-math horizontal conv.
//  - LDS entry per column = uint4{p01,p23,g01,g23} (f16 pairs along rows)
//    -> 1 ds_read_b128 per tap (was 2), pk_fma/pk_mul hconv (176 vs 352
//    VALU/group), h outputs already f16-paired for the fdot2 scatter
//  - vertical 11-tap conv: shift window, 14 slots x 5 fields f32, fdot2
//  - unified tail (group 10 = rows 40,41 + zero rows; emit guard oo<32)
//  - unroll 2 halves the shift-mov overhead
// History: R4 runtime-idx ring spilled; R5 (512,4) VGPR cap spilled; R7
// combined hconv; R10 dot2 scatter (58.6us, VALUBusy 73%).

#define KW 11
#define HALF 5
#define STRIP 32
#define W 512
#define H 512
#define NT 512
#define SCOLS (W + 2*HALF)    // 522
#define NSLOT 14

static constexpr float kC1 = 0.0001f;
static constexpr float kC2 = 0.0009f;

typedef decltype(__builtin_amdgcn_cvt_pkrtz(0.f, 0.f)) half2v;

__device__ __forceinline__ float sgpr_f(float v) {
    return __int_as_float(__builtin_amdgcn_readfirstlane(__float_as_int(v)));
}
__device__ __forceinline__ int bci(half2v h) {
    return __builtin_bit_cast(int, h);
}
__device__ __forceinline__ half2v bch(int i) {
    return __builtin_bit_cast(half2v, i);
}

__global__ __launch_bounds__(NT, 2) void ssim_strip(
    const float* __restrict__ logits,
    const float* __restrict__ gts,
    const float* __restrict__ window,
    float* __restrict__ partial)
{
    __shared__ uint4 sq[2][SCOLS];   // {p01,p23,g01,g23} f16-pair bits
    __shared__ float red[NT / 64];

    const int x = threadIdx.x;

    // 1D taps = row sums of 2D window (sum(g)=1); SGPR-hoisted.
    float w[KW];
#pragma unroll
    for (int k = 0; k < KW; ++k) {
        float s = 0.f;
#pragma unroll
        for (int j = 0; j < KW; ++j) s += window[k * KW + j];
        w[k] = sgpr_f(s);
    }

    // f16 tap pairs (wk,wk) for pk hconv, SGPR ints.
    int wk2i[KW];
#pragma unroll
    for (int k = 0; k < KW; ++k)
        wk2i[k] = __builtin_amdgcn_readfirstlane(
            bci(__builtin_amdgcn_cvt_pkrtz(w[k], w[k])));

    // f16 weight pairs for the vertical scatter (slot p, row-pairs):
    //   rows (0,1): (w[10-p], w[11-p])   valid p=0..11
    //   rows (2,3): (w[12-q], w[13-q])   valid q=2..13
    int wpAi[12], wpBi[12];
#pragma unroll
    for (int p = 0; p < 12; ++p) {
        const float a0 = (10 - p >= 0 && 10 - p <= 10) ? w[10 - p] : 0.f;
        const float a1 = (11 - p >= 0 && 11 - p <= 10) ? w[11 - p] : 0.f;
        wpAi[p] = __builtin_amdgcn_readfirstlane(
            bci(__builtin_amdgcn_cvt_pkrtz(a0, a1)));
        const int q = p + 2;
        const float b0 = (12 - q >= 0 && 12 - q <= 10) ? w[12 - q] : 0.f;
        const float b1 = (13 - q >= 0 && 13 - q <= 10) ? w[13 - q] : 0.f;
        wpBi[p] = __builtin_amdgcn_readfirstlane(
            bci(__builtin_amdgcn_cvt_pkrtz(b0, b1)));
    }

    const int img = blockIdx.x >> 4;
    const int ty  = blockIdx.x & 15;
    const int y0  = ty * STRIP;
    const float* __restrict__ L = logits + (size_t)img * (H * W);
    const float* __restrict__ G = gts    + (size_t)img * (H * W);

    // zero halo columns once, both buffers
    if (x < 2 * HALF) {
        const int sc = (x < HALF) ? x : (W + x);
        sq[0][sc] = make_uint4(0, 0, 0, 0);
        sq[1][sc] = make_uint4(0, 0, 0, 0);
    }

    float P1[NSLOT], P2[NSLOT], PA[NSLOT], PB[NSLOT], PC[NSLOT];
#pragma unroll
    for (int i = 0; i < NSLOT; ++i) {
        P1[i] = 0.f; P2[i] = 0.f; PA[i] = 0.f; PB[i] = 0.f; PC[i] = 0.f;
    }

    // prefetch+preprocess: pl = masked sigmoid(logit), pgv = masked gt
    float pl[4], pgv[4];
#define PREFETCH_ROW(j, rr_expr)                                               \
    {                                                                          \
        const int row  = y0 - HALF + (rr_expr);                                \
        const int rowc = min(max(row, 0), H - 1);                              \
        const float mk = (row == rowc) ? 1.f : 0.f;                            \
        const float lv = L[rowc * W + x];                                      \
        const float gv = G[rowc * W + x];                                      \
        pl[j]  = mk * __builtin_amdgcn_rcpf(1.f + __expf(-lv));                \
        pgv[j] = mk * gv;                                                      \
    }
#pragma unroll
    for (int j = 0; j < 4; ++j) PREFETCH_ROW(j, j)

    float acc = 0.f;

#pragma unroll 2
    for (int g = 0; g <= 10; ++g) {
        const int b = g & 1;

        // ---- stage group g as f16 pairs: one b128 write ----
        {
            uint4 q;
            q.x = (unsigned)bci(__builtin_amdgcn_cvt_pkrtz(pl[0],  pl[1]));
            q.y = (unsigned)bci(__builtin_amdgcn_cvt_pkrtz(pl[2],  pl[3]));
            q.z = (unsigned)bci(__builtin_amdgcn_cvt_pkrtz(pgv[0], pgv[1]));
            q.w = (unsigned)bci(__builtin_amdgcn_cvt_pkrtz(pgv[2], pgv[3]));
            sq[b][x + HALF] = q;
        }

        // ---- prefetch next group ----
        if (g < 9) {
#pragma unroll
            for (int j = 0; j < 4; ++j) PREFETCH_ROW(j, 4 * (g + 1) + j)
        } else if (g == 9) {
            PREFETCH_ROW(0, 40)
            PREFETCH_ROW(1, 41)
            pl[2] = 0.f; pl[3] = 0.f; pgv[2] = 0.f; pgv[3] = 0.f;
        }

        __syncthreads();   // double-buffered: one barrier per group

        // ---- packed-f16 horizontal conv: 11 b128 reads, pk_fma math ----
        const half2v hz = bch(0);
        half2v h1a = hz, h1b = hz, h2a = hz, h2b = hz;
        half2v hAa = hz, hAb = hz, hBa = hz, hBb = hz;
        half2v hCa = hz, hCb = hz;
#pragma unroll
        for (int k = 0; k < KW; ++k) {
            const uint4 q = sq[b][x + k];
            const half2v p01 = bch((int)q.x), p23 = bch((int)q.y);
            const half2v g01 = bch((int)q.z), g23 = bch((int)q.w);
            const half2v wk2 = bch(wk2i[k]);
            h1a += wk2 * p01;          h1b += wk2 * p23;
            h2a += wk2 * g01;          h2b += wk2 * g23;
            hAa += wk2 * (p01 * p01);  hAb += wk2 * (p23 * p23);
            hBa += wk2 * (g01 * g01);  hBb += wk2 * (g23 * g23);
            hCa += wk2 * (p01 * g01);  hCb += wk2 * (p23 * g23);
        }

        // ---- vertical scatter via fdot2 (f32 accumulators) ----
#pragma unroll
        for (int p = 0; p < 12; ++p) {
            const half2v wa = bch(wpAi[p]);
            P1[p] = __builtin_amdgcn_fdot2(h1a, wa, P1[p], false);
            P2[p] = __builtin_amdgcn_fdot2(h2a, wa, P2[p], false);
            PA[p] = __builtin_amdgcn_fdot2(hAa, wa, PA[p], false);
            PB[p] = __builtin_amdgcn_fdot2(hBa, wa, PB[p], false);
            PC[p] = __builtin_amdgcn_fdot2(hCa, wa, PC[p], false);
        }
#pragma unroll
        for (int p = 2; p < 14; ++p) {
            const half2v wb = bch(wpBi[p - 2]);
            P1[p] = __builtin_amdgcn_fdot2(h1b, wb, P1[p], false);
            P2[p] = __builtin_amdgcn_fdot2(h2b, wb, P2[p], false);
            PA[p] = __builtin_amdgcn_fdot2(hAb, wb, PA[p], false);
            PB[p] = __builtin_amdgcn_fdot2(hBb, wb, PB[p], false);
            PC[p] = __builtin_amdgcn_fdot2(hCb, wb, PC[p], false);
        }

        // ---- emit completed slots (oo = 4g-10+p), shift window by 4 ----
        const int oo0 = 4 * g - 10;
#pragma unroll
        for (int p = 0; p < 4; ++p) {
            const int oo = oo0 + p;
            if (oo >= 0 && oo < STRIP) {
                const float m1 = P1[p], m2 = P2[p];
                const float mu11 = m1 * m1, mu22 = m2 * m2, mu12 = m1 * m2;
                const float s11 = PA[p] - mu11;
                const float s22 = PB[p] - mu22;
                const float s12 = PC[p] - mu12;
                const float num = (2.f * mu12 + kC1) * (2.f * s12 + kC2);
                const float den = (mu11 + mu22 + kC1) * (s11 + s22 + kC2);
                acc += num * __builtin_amdgcn_rcpf(den);
            }
        }
#pragma unroll
        for (int i = 0; i < NSLOT - 4; ++i) {
            P1[i] = P1[i + 4]; P2[i] = P2[i + 4];
            PA[i] = PA[i + 4]; PB[i] = PB[i + 4]; PC[i] = PC[i + 4];
        }
#pragma unroll
        for (int i = NSLOT - 4; i < NSLOT; ++i) {
            P1[i] = 0.f; P2[i] = 0.f; PA[i] = 0.f; PB[i] = 0.f; PC[i] = 0.f;
        }
    }

    // ---- block reduction ----
#pragma unroll
    for (int off = 32; off > 0; off >>= 1) acc += __shfl_xor(acc, off);
    if ((x & 63) == 0) red[x >> 6] = acc;
    __syncthreads();
    if (x == 0) {
        float s = 0.f;
#pragma unroll
        for (int i = 0; i < NT / 64; ++i) s += red[i];
        partial[blockIdx.x] = s;
    }
#undef PREFETCH_ROW
}

__global__ __launch_bounds__(256) void ssim_finalize(
    const float* __restrict__ partial, int nparts, double inv_count,
    float* __restrict__ out)
{
    __shared__ double sd[256];
    const int tid = threadIdx.x;
    double s = 0.0;
    for (int i = tid; i < nparts; i += 256) s += (double)partial[i];
    sd[tid] = s;
    __syncthreads();
    for (int st = 128; st > 0; st >>= 1) {
        if (tid < st) sd[tid] += sd[tid + st];
        __syncthreads();
    }
    if (tid == 0) out[0] = (float)(1.0 - sd[0] * inv_count);
}

extern "C" void kernel_launch(void* const* d_in, const int* in_sizes, int n_in,
                              void* d_out, int out_size, void* d_ws, size_t ws_size,
                              hipStream_t stream) {
    const float* logits = (const float*)d_in[0];
    const float* gts    = (const float*)d_in[1];
    const float* window = (const float*)d_in[2];
    float* out = (float*)d_out;

    const int nimg = in_sizes[0] / (H * W);   // 32
    const int nblocks = nimg * (H / STRIP);   // 512

    float* partial = (float*)d_ws;

    ssim_strip<<<nblocks, NT, 0, stream>>>(logits, gts, window, partial);

    const double inv_count = 1.0 / ((double)nimg * H * W);
    ssim_finalize<<<1, 256, 0, stream>>>(partial, nblocks, inv_count, out);
}